// Round 8
// baseline (417.993 us; speedup 1.0000x reference)
//
#include <hip/hip_runtime.h>

#define BATCH 128
#define CH    768
#define HW    576      // 24*24
#define NTOK  144      // 12*12 tokens
#define NMERGE 72
#define NKEEP 360      // 72*1 + 72*4 output tokens
#define CCH   16       // channels per score chunk
#define NCH   48       // score chunks (768/16)
#define SB    384      // score block threads (6 waves)
#define SBLK  9        // score blocks per batch (48*72/384)
#define GC    16       // channels per gather block
#define LP    580      // LDS row pad (16B-aligned -> ds_write_b128; reads 2-way max)

typedef float f32x4 __attribute__((ext_vector_type(4)));

// ---------------------------------------------------------------------------
// Kernel 1: score + fused select. 9 blocks per batch; each thread scores 2
// adjacent tokens over 16 channels (two float4 loads/channel, fully coalesced,
// x read exactly once, fixed-order deterministic sums). The last block of a
// batch to finish (device-scope atomic counter) runs the selection inline:
// stable rank -> keep flags -> closed-form per-pixel output position from
// keep-prefix tables (no 576-wide ballot needed).
// ---------------------------------------------------------------------------
__global__ __launch_bounds__(SB) void score_select(const float* __restrict__ x,
                                                   float* __restrict__ part,
                                                   int* __restrict__ cnt,
                                                   float* __restrict__ tok_f,
                                                   int* __restrict__ tok_i) {
    int tid = threadIdx.x;
    int b   = blockIdx.x / SBLK;
    int w   = (blockIdx.x % SBLK) * SB + tid;    // 0..3455 within batch
    int ch  = w / 72;
    int tp  = w - ch * 72;
    int i   = tp / 6, jp = tp - i * 6;
    const float* xb = x + ((size_t)b * CH + (size_t)ch * CCH) * HW + i * 48 + jp * 4;
    float acc0 = 0.f, acc1 = 0.f;
#pragma unroll
    for (int cc = 0; cc < CCH; ++cc) {
        float4 v0 = *(const float4*)(xb + (size_t)cc * HW);        // even row
        float4 v1 = *(const float4*)(xb + (size_t)cc * HW + 24);   // odd row
        acc0 += fabsf(v0.y - v0.x) + fabsf(v1.x - v0.x) + fabsf(v1.y - v0.x);
        acc1 += fabsf(v0.w - v0.z) + fabsf(v1.z - v0.z) + fabsf(v1.w - v0.z);
    }
    int t0 = i * 12 + jp * 2;
    *(float2*)(part + ((size_t)b * NCH + ch) * NTOK + t0) = make_float2(acc0, acc1);

    // ---- completion handshake (device scope; L2s not cross-XCD coherent) ----
    __shared__ int lastflag;
    __threadfence();                     // flush this thread's part writes
    __syncthreads();
    if (tid == 0) lastflag = (atomicAdd(&cnt[b], 1) == SBLK - 1);
    __syncthreads();
    if (!lastflag) return;
    __threadfence();                     // acquire: see other blocks' part writes

    // ---- selection for batch b ----
    __shared__ float s[NTOK];
    __shared__ int   keep[NTOK];
    __shared__ int   keeppre[12][13];    // keeppre[i][j] = #keep in token-row i, cols < j
    __shared__ int   rowpre[24];
    if (tid < NTOK) {
        float v = 0.f;
        for (int c8 = 0; c8 < NCH; ++c8)
            v += part[((size_t)b * NCH + c8) * NTOK + tid];
        s[tid] = v;
    }
    __syncthreads();
    if (tid < NTOK) {
        float v = s[tid];
        int rank = 0;
        for (int u = 0; u < NTOK; ++u) {
            float su = s[u];
            rank += (su < v) || (su == v && u < tid);   // stable argsort rank
        }
        keep[tid] = (rank >= NMERGE);
    }
    __syncthreads();
    if (tid < 12) {
        int pre = 0;
        for (int j = 0; j < 12; ++j) { keeppre[tid][j] = pre; pre += keep[tid * 12 + j]; }
        keeppre[tid][12] = pre;
    }
    __syncthreads();
    if (tid == 0) {
        int pre = 0;
        for (int r = 0; r < 24; ++r) {
            rowpre[r] = pre;
            int K = keeppre[r >> 1][12];
            pre += (r & 1) ? 2 * K : 12 + K;
        }
    }
    __syncthreads();
    for (int p = tid; p < HW; p += SB) {
        int r = p / 24, c = p - r * 24, ti = r >> 1, tj = c >> 1;
        bool kp = keep[ti * 12 + tj];
        bool inc = kp || (((r & 1) == 0) && ((c & 1) == 0));
        if (inc) {
            int pos;
            if ((r & 1) == 0) pos = rowpre[r] + ((c + 1) >> 1) + keeppre[ti][c >> 1];
            else              pos = rowpre[r] + 2 * keeppre[ti][tj] + (c & 1);
            tok_f[(size_t)b * NKEEP + pos] = (float)p;   // output 1 (as float)
            tok_i[(size_t)b * NKEEP + pos] = p;          // for gather kernel
        }
    }
}

// ---------------------------------------------------------------------------
// Kernel 2: gather + transpose via full-row LDS staging. Block = (b, 16-ch
// tile). Stage 16 full rows coalesced (true ds_write_b128 thanks to LP=580);
// gather-read phase <=2-way bank aliasing (free). float4 nontemporal stores:
// each 4-lane cluster writes 64 contiguous bytes.
// ---------------------------------------------------------------------------
__global__ __launch_bounds__(256) void gather_kernel(const float* __restrict__ x,
                                                     const int* __restrict__ tok_i,
                                                     float* __restrict__ out) {
    __shared__ float lds[GC * LP];         // [c][p], pad 580 (37.1 KB)
    __shared__ int tok[NKEEP];
    int b = blockIdx.y, ct = blockIdx.x;   // 48 channel tiles
    int tid = threadIdx.x;
    for (int k = tid; k < NKEEP; k += 256) tok[k] = tok_i[(size_t)b * NKEEP + k];
    const float* xb = x + ((size_t)b * CH + (size_t)ct * GC) * HW;
#pragma unroll
    for (int q = 0; q < 9; ++q) {          // 16*144 float4s / 256 threads
        int idx = q * 256 + tid;
        int c = idx / 144, p4 = (idx - c * 144) * 4;
        float4 v = *(const float4*)(xb + (size_t)c * HW + p4);
        *(float4*)&lds[c * LP + p4] = v;   // 16B-aligned: one ds_write_b128
    }
    __syncthreads();
    int c4 = (tid & 3) * 4, kh = tid >> 2; // 64 k-groups, 4 channels each
    float* ob = out + (size_t)b * NKEEP * CH + (size_t)ct * GC + c4;
#pragma unroll
    for (int it = 0; it < 6; ++it) {
        int k = it * 64 + kh;              // last iter masked (320..383 vs 360)
        if (k < NKEEP) {
            int p = tok[k];
            f32x4 v;
            v.x = lds[(c4 + 0) * LP + p];
            v.y = lds[(c4 + 1) * LP + p];
            v.z = lds[(c4 + 2) * LP + p];
            v.w = lds[(c4 + 3) * LP + p];
            __builtin_nontemporal_store(v, (f32x4*)(ob + (size_t)k * CH));
        }
    }
}

extern "C" void kernel_launch(void* const* d_in, const int* in_sizes, int n_in,
                              void* d_out, int out_size, void* d_ws, size_t ws_size,
                              hipStream_t stream) {
    const float* x = (const float*)d_in[0];
    float* outf = (float*)d_out;
    float* part = (float*)d_ws;                                   // 128*48*144 f32
    char* wsc = (char*)d_ws + (size_t)BATCH * NCH * NTOK * sizeof(float);
    int* tok_i = (int*)wsc;                                       // 128*360 int
    int* cnt = (int*)(wsc + (size_t)BATCH * NKEEP * sizeof(int)); // 128 int
    float* tok_f = outf + (size_t)BATCH * NKEEP * CH;             // token_idx area

    (void)hipMemsetAsync(cnt, 0, BATCH * sizeof(int), stream);
    score_select<<<dim3(BATCH * SBLK), SB, 0, stream>>>(x, part, cnt, tok_f, tok_i);
    gather_kernel<<<dim3(48, BATCH), 256, 0, stream>>>(x, tok_i, outf);
}

// Round 11
// 99.994 us; speedup vs baseline: 4.1802x; 4.1802x over previous
//
#include <hip/hip_runtime.h>

#define BATCH 128
#define CH    768
#define HW    576      // 24*24
#define NTOK  144      // 12*12 tokens
#define NMERGE 72
#define NKEEP 360      // 72*1 + 72*4 output tokens
#define CCH   16       // channels per score chunk
#define NCH   48       // score chunks (768/16)
#define GC    16       // channels per gather block
#define LP    580      // LDS row pad (16B-aligned -> ds_write_b128; reads <=2-way)

typedef float f32x4 __attribute__((ext_vector_type(4)));

// ---------------------------------------------------------------------------
// Kernel 1: per-(b, chunk, token-pair) partial scores. No LDS, no syncs.
// Thread owns 2 adjacent tokens; two float4 loads per channel cover the
// even row (both anchors + right pixels) and the full odd row. Fully
// coalesced; x is read exactly once. Deterministic fixed-order summation.
// ---------------------------------------------------------------------------
__global__ __launch_bounds__(256) void score_kernel(const float* __restrict__ x,
                                                    float* __restrict__ part) {
    int w  = blockIdx.x * 256 + threadIdx.x;     // 128*48*72 work items, no tail
    int b  = w / (NCH * 72);
    int r  = w - b * (NCH * 72);
    int ch = r / 72;
    int tp = r - ch * 72;
    int i  = tp / 6, jp = tp - i * 6;            // token row, token-pair col
    const float* xb = x + ((size_t)b * CH + (size_t)ch * CCH) * HW + i * 48 + jp * 4;
    float acc0 = 0.f, acc1 = 0.f;
#pragma unroll
    for (int cc = 0; cc < CCH; ++cc) {
        float4 v0 = *(const float4*)(xb + (size_t)cc * HW);        // even row
        float4 v1 = *(const float4*)(xb + (size_t)cc * HW + 24);   // odd row
        acc0 += fabsf(v0.y - v0.x) + fabsf(v1.x - v0.x) + fabsf(v1.y - v0.x);
        acc1 += fabsf(v0.w - v0.z) + fabsf(v1.z - v0.z) + fabsf(v1.w - v0.z);
    }
    int t0 = i * 12 + jp * 2;
    *(float2*)(part + ((size_t)b * NCH + ch) * NTOK + t0) = make_float2(acc0, acc1);
}

// ---------------------------------------------------------------------------
// Kernel 2: per-batch. Reduce partials -> scores, rank (stable), build the
// per-pixel include mask, prefix-sum via ballot/popcount, emit token_idx
// (float into d_out tail, int into ws for the gather). 576 thr = 9 waves.
// ---------------------------------------------------------------------------
__global__ __launch_bounds__(576) void select_kernel(const float* __restrict__ part,
                                                     float* __restrict__ tok_f,
                                                     int* __restrict__ tok_i) {
    int b = blockIdx.x;
    int tid = threadIdx.x;
    __shared__ float s[NTOK];
    __shared__ int   merged[NTOK];
    __shared__ unsigned long long wmask[9];

    if (tid < NTOK) {
        float v = 0.f;
        for (int ch = 0; ch < NCH; ++ch)
            v += part[((size_t)b * NCH + ch) * NTOK + tid];
        s[tid] = v;
    }
    __syncthreads();
    if (tid < NTOK) {
        float v = s[tid];
        int rank = 0;
        for (int u = 0; u < NTOK; ++u) {
            float su = s[u];
            rank += (su < v) || (su == v && u < tid);   // stable argsort rank
        }
        merged[tid] = (rank < NMERGE);
    }
    __syncthreads();

    // tid = pixel p in [0,576)
    int row = tid / 24, col = tid % 24;
    int t = (row >> 1) * 12 + (col >> 1);
    bool inc = merged[t] ? ((row & 1) == 0 && (col & 1) == 0) : true;
    unsigned long long mask = __ballot(inc);
    int wv = tid >> 6, lane = tid & 63;
    if (lane == 0) wmask[wv] = mask;
    __syncthreads();
    int pos = 0;
    for (int w = 0; w < wv; ++w) pos += __popcll(wmask[w]);
    pos += __popcll(mask & ((1ULL << lane) - 1ULL));
    if (inc) {
        tok_f[(size_t)b * NKEEP + pos] = (float)tid;  // output 1 (as float)
        tok_i[(size_t)b * NKEEP + pos] = tid;         // for gather kernel
    }
}

// ---------------------------------------------------------------------------
// Kernel 3: gather + transpose via full-row LDS staging. Block = (b, 16-ch
// tile). Stage 16 full rows coalesced (true ds_write_b128 thanks to LP=580);
// gather-read phase <=2-way bank aliasing (free). Clustered f32x4
// nontemporal stores: each 4-lane cluster writes 64 contiguous bytes.
// ---------------------------------------------------------------------------
__global__ __launch_bounds__(256) void gather_kernel(const float* __restrict__ x,
                                                     const int* __restrict__ tok_i,
                                                     float* __restrict__ out) {
    __shared__ float lds[GC * LP];         // [c][p], pad 580 (37.1 KB)
    __shared__ int tok[NKEEP];
    int b = blockIdx.y, ct = blockIdx.x;   // 48 channel tiles
    int tid = threadIdx.x;
    for (int k = tid; k < NKEEP; k += 256) tok[k] = tok_i[(size_t)b * NKEEP + k];
    const float* xb = x + ((size_t)b * CH + (size_t)ct * GC) * HW;
#pragma unroll
    for (int q = 0; q < 9; ++q) {          // 16*144 float4s / 256 threads
        int idx = q * 256 + tid;
        int c = idx / 144, p4 = (idx - c * 144) * 4;
        float4 v = *(const float4*)(xb + (size_t)c * HW + p4);
        *(float4*)&lds[c * LP + p4] = v;   // 16B-aligned: one ds_write_b128
    }
    __syncthreads();
    int c4 = (tid & 3) * 4, kh = tid >> 2; // 64 k-groups, 4 channels each
    float* ob = out + (size_t)b * NKEEP * CH + (size_t)ct * GC + c4;
#pragma unroll
    for (int it = 0; it < 6; ++it) {
        int k = it * 64 + kh;              // last iter masked (320..383 vs 360)
        if (k < NKEEP) {
            int p = tok[k];
            f32x4 v;
            v.x = lds[(c4 + 0) * LP + p];
            v.y = lds[(c4 + 1) * LP + p];
            v.z = lds[(c4 + 2) * LP + p];
            v.w = lds[(c4 + 3) * LP + p];
            __builtin_nontemporal_store(v, (f32x4*)(ob + (size_t)k * CH));
        }
    }
}

extern "C" void kernel_launch(void* const* d_in, const int* in_sizes, int n_in,
                              void* d_out, int out_size, void* d_ws, size_t ws_size,
                              hipStream_t stream) {
    const float* x = (const float*)d_in[0];
    float* outf = (float*)d_out;
    float* part = (float*)d_ws;                                   // 128*48*144 f32
    int* tok_i = (int*)((char*)d_ws + (size_t)BATCH * NCH * NTOK * sizeof(float));
    float* tok_f = outf + (size_t)BATCH * NKEEP * CH;             // token_idx area

    score_kernel<<<dim3(BATCH * NCH * 72 / 256), 256, 0, stream>>>(x, part);
    select_kernel<<<dim3(BATCH), 576, 0, stream>>>(part, tok_f, tok_i);
    gather_kernel<<<dim3(48, BATCH), 256, 0, stream>>>(x, tok_i, outf);
}